// Round 2
// baseline (466.901 us; speedup 1.0000x reference)
//
#include <hip/hip_runtime.h>
#include <stdint.h>

// Must match numpy's unfused mul/sub/add + IEEE div exactly: no FMA
// contraction anywhere in this TU (only nms_mask does fp math anyway).
#pragma clang fp contract(off)

#define N        8192
#define NCHUNK   128      // N / 64
#define MAX_OUT  300
#define THRESH   0.5f

// ---------------------------------------------------------------------------
// Phase 1: rank sort. Stable argsort of -scores (descending score, ties by
// ascending original index). Keys are unique (index tie-break), so ranks are
// a permutation -> single scatter fully populates sboxes/sidx.
// ---------------------------------------------------------------------------
__global__ void nms_rank_sort(const float4* __restrict__ rois,
                              const float*  __restrict__ scores,
                              float4* __restrict__ sboxes,
                              int*    __restrict__ sidx) {
    __shared__ uint32_t sk[N];   // 32 KiB: score bits (scores >= 0 -> monotonic as uint)
    const int tid = threadIdx.x;
    for (int j = tid; j < N; j += blockDim.x)
        sk[j] = __float_as_uint(scores[j]);
    __syncthreads();

    const int i = blockIdx.x * blockDim.x + tid;
    const uint32_t my = sk[i];
    int rank = 0;
#pragma unroll 8
    for (int j = 0; j < N; ++j) {
        uint32_t v = sk[j];
        // j sorts before i  <=>  score_j > score_i, or equal score and j < i
        rank += (v > my) || (v == my && j < i);
    }
    sidx[rank]   = i;
    sboxes[rank] = rois[i];
}

// ---------------------------------------------------------------------------
// Phase 2: suppression bitmask, upper triangle only.
// mask[r][bj] bit c set  <=>  IoU(box_r, box_{bj*64+c}) > 0.5 and col > r.
// ---------------------------------------------------------------------------
__global__ void nms_mask(const float4* __restrict__ sboxes,
                         uint64_t* __restrict__ mask) {
    const int bj = blockIdx.x;   // column chunk
    const int bi = blockIdx.y;   // row chunk
    if (bj < bi) return;         // lower triangle never read

    __shared__ float4 cb[64];
    const int t = threadIdx.x;   // 0..63
    cb[t] = sboxes[bj * 64 + t];
    __syncthreads();

    const int r = bi * 64 + t;
    const float4 rb = sboxes[r];
    const float ar = (rb.z - rb.x) * (rb.w - rb.y);

    uint64_t bits = 0;
    for (int c = 0; c < 64; ++c) {
        const int col = bj * 64 + c;
        const float4 b = cb[c];
        float ac    = (b.z - b.x) * (b.w - b.y);
        float lx    = fmaxf(rb.x, b.x);
        float ly    = fmaxf(rb.y, b.y);
        float hx    = fminf(rb.z, b.z);
        float hy    = fminf(rb.w, b.w);
        float w     = fmaxf(hx - lx, 0.0f);
        float h     = fmaxf(hy - ly, 0.0f);
        float inter = w * h;
        float denom = ar + ac - inter;   // left-to-right like numpy
        float iou   = inter / denom;     // IEEE fp32 div (no fast-math)
        if (iou > THRESH && col > r) bits |= (1ull << c);
    }
    mask[(size_t)r * NCHUNK + bj] = bits;
}

// ---------------------------------------------------------------------------
// Phase 3: greedy serial scan. One wave; lane l owns removed chunks l and l+64
// in registers. Early-exit at MAX_OUT kept (suppression is forward-only, so
// later boxes cannot affect the first 300 kept).
// ---------------------------------------------------------------------------
__global__ void nms_scan(const uint64_t* __restrict__ mask,
                         const int*      __restrict__ sidx,
                         int*            __restrict__ out) {
    const int lane = threadIdx.x;          // 0..63
    uint64_t rem0 = 0, rem1 = 0;           // chunks lane, lane+64
    int kept = 0;

    for (int c = 0; c < NCHUNK; ++c) {
        // broadcast current removed word for chunk c (owner lane = c & 63)
        uint64_t sel = (c < 64) ? rem0 : rem1;
        uint64_t w = __shfl((unsigned long long)sel, c & 63, 64);

        uint64_t remw;
        if (w == ~0ull) {
            remw = w;                      // whole chunk already suppressed
        } else {
            // lane l holds the diagonal word of row c*64+l (bits only for cols > row)
            uint64_t diag = mask[(size_t)(c * 64 + lane) * NCHUNK + c];
            remw = w;
#pragma unroll
            for (int l = 0; l < 64; ++l) {
                uint64_t dl = __shfl((unsigned long long)diag, l, 64);
                if (!((remw >> l) & 1)) remw |= dl;   // box l kept -> suppress within chunk
            }
        }

        const uint64_t keptmask = ~remw;   // forward-only bits: final 0-bits == kept
        const int nk = __popcll(keptmask);

        if ((keptmask >> lane) & 1) {
            int pos = kept + __popcll(keptmask & ((1ull << lane) - 1ull));
            if (pos < MAX_OUT) out[pos] = sidx[c * 64 + lane];
        }
        kept += nk;
        if (kept >= MAX_OUT) break;

        // write resolved word back to its owner lane
        if (c < 64) { if (lane == c)      rem0 = remw; }
        else        { if (lane == c - 64) rem1 = remw; }

        // OR kept rows into strictly-future chunks (chunks < c are unwritten ws!)
        uint64_t m = keptmask;
        while (m) {
            int l = __ffsll((long long)m) - 1;
            m &= m - 1;
            size_t row = (size_t)(c * 64 + l) * NCHUNK;
            if (lane > c)      rem0 |= mask[row + lane];
            if (64 + lane > c) rem1 |= mask[row + 64 + lane];
        }
    }

    // pad remaining slots with -1
    for (int p = kept + lane; p < MAX_OUT; p += 64) out[p] = -1;
}

// ---------------------------------------------------------------------------
extern "C" void kernel_launch(void* const* d_in, const int* in_sizes, int n_in,
                              void* d_out, int out_size, void* d_ws, size_t ws_size,
                              hipStream_t stream) {
    const float4* rois   = (const float4*)d_in[0];   // [8192,4] fp32
    const float*  scores = (const float*)d_in[1];    // [8192]   fp32
    int* out = (int*)d_out;                          // [300] int32

    // workspace layout (needs ~8.35 MB)
    float4*   sboxes = (float4*)d_ws;                                  // 128 KiB
    int*      sidx   = (int*)((char*)d_ws + 128 * 1024);               //  32 KiB
    uint64_t* mask   = (uint64_t*)((char*)d_ws + 160 * 1024);          //   8 MiB

    nms_rank_sort<<<dim3(32), dim3(256), 0, stream>>>(rois, scores, sboxes, sidx);
    nms_mask<<<dim3(NCHUNK, NCHUNK), dim3(64), 0, stream>>>(sboxes, mask);
    nms_scan<<<dim3(1), dim3(64), 0, stream>>>(mask, sidx, out);
}

// Round 3
// 277.408 us; speedup vs baseline: 1.6831x; 1.6831x over previous
//
#include <hip/hip_runtime.h>
#include <stdint.h>

// Must match numpy's unfused mul/sub/add + IEEE div exactly: no FMA
// contraction anywhere in this TU (only nms_mask does fp math anyway).
#pragma clang fp contract(off)

#define N        8192
#define NCHUNK   128      // N / 64
#define MAX_OUT  300
#define THRESH   0.5f

// ---------------------------------------------------------------------------
// Phase 1a: partial rank counts. Block (bi,bj): i-chunk bi (256 rows) vs
// j-chunk bj (256 cols). Stable-argsort comparator on (score desc, idx asc);
// keys unique via index tie-break -> final ranks are a permutation.
// ---------------------------------------------------------------------------
__global__ void nms_rank_partial(const float* __restrict__ scores,
                                 int* __restrict__ rank) {
    __shared__ uint32_t sk[256];
    const int tid = threadIdx.x;
    const int bi  = blockIdx.y, bj = blockIdx.x;
    const int jbase = bj * 256;

    sk[tid] = __float_as_uint(scores[jbase + tid]);  // scores >= 0 -> uint-monotonic
    __syncthreads();

    const int i = bi * 256 + tid;
    const uint32_t my = __float_as_uint(scores[i]);

    int cnt = 0;
    const uint4* sk4 = (const uint4*)sk;
    for (int jj = 0; jj < 64; ++jj) {          // 64 x b128 LDS broadcast reads
        uint4 v = sk4[jj];
        int j0 = jbase + jj * 4;
        cnt += (v.x > my) || (v.x == my && (j0 + 0) < i);
        cnt += (v.y > my) || (v.y == my && (j0 + 1) < i);
        cnt += (v.z > my) || (v.z == my && (j0 + 2) < i);
        cnt += (v.w > my) || (v.w == my && (j0 + 3) < i);
    }
    atomicAdd(&rank[i], cnt);
}

// ---------------------------------------------------------------------------
// Phase 1b: scatter boxes/indices into score-sorted order.
// ---------------------------------------------------------------------------
__global__ void nms_scatter(const float4* __restrict__ rois,
                            const int*    __restrict__ rank,
                            float4* __restrict__ sboxes,
                            int*    __restrict__ sidx) {
    const int i = blockIdx.x * blockDim.x + threadIdx.x;
    const int r = rank[i];
    sboxes[r] = rois[i];
    sidx[r]   = i;
}

// ---------------------------------------------------------------------------
// Phase 2: suppression bitmask, upper triangle only.
// mask[r][bj] bit c set  <=>  IoU(box_r, box_{bj*64+c}) > 0.5 and col > r.
// ---------------------------------------------------------------------------
__global__ void nms_mask(const float4* __restrict__ sboxes,
                         uint64_t* __restrict__ mask) {
    const int bj = blockIdx.x;   // column chunk
    const int bi = blockIdx.y;   // row chunk
    if (bj < bi) return;         // lower triangle never read

    __shared__ float4 cb[64];
    const int t = threadIdx.x;   // 0..63
    cb[t] = sboxes[bj * 64 + t];
    __syncthreads();

    const int r = bi * 64 + t;
    const float4 rb = sboxes[r];
    const float ar = (rb.z - rb.x) * (rb.w - rb.y);

    uint64_t bits = 0;
    for (int c = 0; c < 64; ++c) {
        const int col = bj * 64 + c;
        const float4 b = cb[c];
        float ac    = (b.z - b.x) * (b.w - b.y);
        float lx    = fmaxf(rb.x, b.x);
        float ly    = fmaxf(rb.y, b.y);
        float hx    = fminf(rb.z, b.z);
        float hy    = fminf(rb.w, b.w);
        float w     = fmaxf(hx - lx, 0.0f);
        float h     = fmaxf(hy - ly, 0.0f);
        float inter = w * h;
        float denom = ar + ac - inter;   // left-to-right like numpy
        float iou   = inter / denom;     // IEEE fp32 div (no fast-math)
        if (iou > THRESH && col > r) bits |= (1ull << c);
    }
    mask[(size_t)r * NCHUNK + bj] = bits;
}

// ---------------------------------------------------------------------------
// Phase 3: greedy serial scan. One wave; lane l owns removed chunks l and l+64
// in registers. Early-exit at MAX_OUT kept (suppression is forward-only, so
// later boxes cannot affect the first 300 kept).
// ---------------------------------------------------------------------------
__global__ void nms_scan(const uint64_t* __restrict__ mask,
                         const int*      __restrict__ sidx,
                         int*            __restrict__ out) {
    const int lane = threadIdx.x;          // 0..63
    uint64_t rem0 = 0, rem1 = 0;           // chunks lane, lane+64
    int kept = 0;

    for (int c = 0; c < NCHUNK; ++c) {
        // broadcast current removed word for chunk c (owner lane = c & 63)
        uint64_t sel = (c < 64) ? rem0 : rem1;
        uint64_t w = __shfl((unsigned long long)sel, c & 63, 64);

        uint64_t remw;
        if (w == ~0ull) {
            remw = w;                      // whole chunk already suppressed
        } else {
            // lane l holds the diagonal word of row c*64+l (bits only for cols > row)
            uint64_t diag = mask[(size_t)(c * 64 + lane) * NCHUNK + c];
            remw = w;
#pragma unroll
            for (int l = 0; l < 64; ++l) {
                uint64_t dl = __shfl((unsigned long long)diag, l, 64);
                if (!((remw >> l) & 1)) remw |= dl;   // box l kept -> suppress within chunk
            }
        }

        const uint64_t keptmask = ~remw;   // forward-only bits: final 0-bits == kept
        const int nk = __popcll(keptmask);

        if ((keptmask >> lane) & 1) {
            int pos = kept + __popcll(keptmask & ((1ull << lane) - 1ull));
            if (pos < MAX_OUT) out[pos] = sidx[c * 64 + lane];
        }
        kept += nk;
        if (kept >= MAX_OUT) break;

        // write resolved word back to its owner lane
        if (c < 64) { if (lane == c)      rem0 = remw; }
        else        { if (lane == c - 64) rem1 = remw; }

        // OR kept rows into strictly-future chunks (chunks < c are unwritten ws!)
        uint64_t m = keptmask;
        while (m) {
            int l = __ffsll((long long)m) - 1;
            m &= m - 1;
            size_t row = (size_t)(c * 64 + l) * NCHUNK;
            if (lane > c)      rem0 |= mask[row + lane];
            if (64 + lane > c) rem1 |= mask[row + 64 + lane];
        }
    }

    // pad remaining slots with -1
    for (int p = kept + lane; p < MAX_OUT; p += 64) out[p] = -1;
}

// ---------------------------------------------------------------------------
extern "C" void kernel_launch(void* const* d_in, const int* in_sizes, int n_in,
                              void* d_out, int out_size, void* d_ws, size_t ws_size,
                              hipStream_t stream) {
    const float4* rois   = (const float4*)d_in[0];   // [8192,4] fp32
    const float*  scores = (const float*)d_in[1];    // [8192]   fp32
    int* out = (int*)d_out;                          // [300] int32

    // workspace layout (~8.6 MB)
    float4*   sboxes = (float4*)d_ws;                                   // 128 KiB
    int*      sidx   = (int*)((char*)d_ws + 128 * 1024);                //  32 KiB
    uint64_t* mask   = (uint64_t*)((char*)d_ws + 160 * 1024);           //   8 MiB
    int*      rank   = (int*)((char*)d_ws + 160 * 1024 + 8 * 1024 * 1024); // 32 KiB

    hipMemsetAsync(rank, 0, N * sizeof(int), stream);
    nms_rank_partial<<<dim3(32, 32), dim3(256), 0, stream>>>(scores, rank);
    nms_scatter<<<dim3(32), dim3(256), 0, stream>>>(rois, rank, sboxes, sidx);
    nms_mask<<<dim3(NCHUNK, NCHUNK), dim3(64), 0, stream>>>(sboxes, mask);
    nms_scan<<<dim3(1), dim3(64), 0, stream>>>(mask, sidx, out);
}

// Round 4
// 135.909 us; speedup vs baseline: 3.4354x; 2.0411x over previous
//
#include <hip/hip_runtime.h>
#include <stdint.h>

// Must match numpy's unfused mul/sub/add + IEEE div exactly: no FMA
// contraction anywhere in this TU (only nms_mask does fp math anyway).
#pragma clang fp contract(off)

#define N        8192
#define NCHUNK   128      // N / 64
#define MAX_OUT  300
#define THRESH   0.5f

// ---------------------------------------------------------------------------
// Phase 1a: partial rank counts. Block (bi,bj): i-chunk bi (256 rows) vs
// j-chunk bj (256 cols). Stable-argsort comparator on (score desc, idx asc);
// keys unique via index tie-break -> final ranks are a permutation.
// ---------------------------------------------------------------------------
__global__ void nms_rank_partial(const float* __restrict__ scores,
                                 int* __restrict__ rank) {
    __shared__ uint32_t sk[256];
    const int tid = threadIdx.x;
    const int bi  = blockIdx.y, bj = blockIdx.x;
    const int jbase = bj * 256;

    sk[tid] = __float_as_uint(scores[jbase + tid]);  // scores >= 0 -> uint-monotonic
    __syncthreads();

    const int i = bi * 256 + tid;
    const uint32_t my = __float_as_uint(scores[i]);

    int cnt = 0;
    const uint4* sk4 = (const uint4*)sk;
    for (int jj = 0; jj < 64; ++jj) {          // 64 x b128 LDS broadcast reads
        uint4 v = sk4[jj];
        int j0 = jbase + jj * 4;
        cnt += (v.x > my) || (v.x == my && (j0 + 0) < i);
        cnt += (v.y > my) || (v.y == my && (j0 + 1) < i);
        cnt += (v.z > my) || (v.z == my && (j0 + 2) < i);
        cnt += (v.w > my) || (v.w == my && (j0 + 3) < i);
    }
    atomicAdd(&rank[i], cnt);
}

// ---------------------------------------------------------------------------
// Phase 1b: scatter boxes/indices into score-sorted order.
// ---------------------------------------------------------------------------
__global__ void nms_scatter(const float4* __restrict__ rois,
                            const int*    __restrict__ rank,
                            float4* __restrict__ sboxes,
                            int*    __restrict__ sidx) {
    const int i = blockIdx.x * blockDim.x + threadIdx.x;
    const int r = rank[i];
    sboxes[r] = rois[i];
    sidx[r]   = i;
}

// ---------------------------------------------------------------------------
// Phase 2: suppression bitmask, upper triangle only.
// mask[r][bj] bit c set  <=>  IoU(box_r, box_{bj*64+c}) > 0.5 and col > r.
// ---------------------------------------------------------------------------
__global__ void nms_mask(const float4* __restrict__ sboxes,
                         uint64_t* __restrict__ mask) {
    const int bj = blockIdx.x;   // column chunk
    const int bi = blockIdx.y;   // row chunk
    if (bj < bi) return;         // lower triangle never read

    __shared__ float4 cb[64];
    const int t = threadIdx.x;   // 0..63
    cb[t] = sboxes[bj * 64 + t];
    __syncthreads();

    const int r = bi * 64 + t;
    const float4 rb = sboxes[r];
    const float ar = (rb.z - rb.x) * (rb.w - rb.y);

    uint64_t bits = 0;
    for (int c = 0; c < 64; ++c) {
        const int col = bj * 64 + c;
        const float4 b = cb[c];
        float ac    = (b.z - b.x) * (b.w - b.y);
        float lx    = fmaxf(rb.x, b.x);
        float ly    = fmaxf(rb.y, b.y);
        float hx    = fminf(rb.z, b.z);
        float hy    = fminf(rb.w, b.w);
        float w     = fmaxf(hx - lx, 0.0f);
        float h     = fmaxf(hy - ly, 0.0f);
        float inter = w * h;
        float denom = ar + ac - inter;   // left-to-right like numpy
        float iou   = inter / denom;     // IEEE fp32 div (no fast-math)
        if (iou > THRESH && col > r) bits |= (1ull << c);
    }
    mask[(size_t)r * NCHUNK + bj] = bits;
}

// ---------------------------------------------------------------------------
// Phase 3: pipelined greedy scan, 1024 threads.
//  - removed bitmap in LDS (removed32, as uint32 pairs for safe atomicOr)
//  - Phase A: wave 0 resolves chunk c's serial chain from prefetched diag
//             words (pure LDS/SALU; no global ops on the critical path)
//  - Phase B: 1024 threads OR all kept rows into removed in ONE parallel
//             memory round-trip; wave 1 prefetches next chunk's diag
//  - outputs + padding written in one parallel pass at the end
// ---------------------------------------------------------------------------
__global__ void __launch_bounds__(1024)
nms_scan(const uint64_t* __restrict__ mask,
         const int*      __restrict__ sidx,
         int*            __restrict__ out) {
    __shared__ uint32_t removed32[2 * NCHUNK];   // 1 KB: removed bitmap, lo/hi pairs
    __shared__ uint64_t diag_lds[2][64];         // 1 KB: double-buffered diagonal words
    __shared__ uint64_t s_kmask[NCHUNK];         // 1 KB: per-chunk kept masks
    __shared__ int      s_kbase[NCHUNK];         // 512 B: kept count before chunk
    __shared__ int      s_keptlist[64];          // kept lanes of current chunk
    __shared__ int      s_kept, s_done, s_nchunks, s_k;

    const int t    = threadIdx.x;
    const int lane = t & 63;

    if (t < 2 * NCHUNK) removed32[t] = 0;
    if (t < 64) diag_lds[0][t] = mask[(size_t)t * NCHUNK + 0];  // diag of chunk 0
    __syncthreads();

    int kept = 0;                                // wave0-uniform mirror of s_kept
    for (int c = 0; c < NCHUNK; ++c) {
        // ---- Phase A: wave 0 resolves the in-chunk greedy chain ----
        if (t < 64) {
            uint64_t remw = (uint64_t)removed32[2 * c] |
                            ((uint64_t)removed32[2 * c + 1] << 32);
            uint64_t dg = diag_lds[c & 1][lane];
            uint64_t keptmask = 0;
            if (remw != ~0ull) {
#pragma unroll
                for (int l = 0; l < 64; ++l) {
                    uint64_t dl = __shfl((unsigned long long)dg, l, 64);
                    if (!((remw >> l) & 1)) remw |= dl;  // box l kept -> suppress in-chunk
                }
                keptmask = ~remw;
            }
            const int nk = __popcll(keptmask);
            if ((keptmask >> lane) & 1) {
                int lpos = __popcll(keptmask & ((1ull << lane) - 1ull));
                s_keptlist[lpos] = lane;
            }
            if (lane == 0) {
                s_kmask[c]  = keptmask;
                s_kbase[c]  = kept;
                s_k         = nk;
                int nkept   = kept + nk;
                s_kept      = nkept;
                // also stop at last chunk so phase B never prefetches OOB
                s_done      = (nkept >= MAX_OUT) || (c == NCHUNK - 1);
                s_nchunks   = c + 1;
            }
            kept += nk;
        }
        __syncthreads();
        if (s_done) break;

        // ---- Phase B: parallel OR of kept rows into future columns ----
        {
            const int col = t & 127;
            const int g   = t >> 7;              // 0..7: 8 threads per column word
            if (t >= 64 && t < 128) {            // wave 1: prefetch next diag
                int l = t - 64;
                diag_lds[(c + 1) & 1][l] =
                    mask[(size_t)((c + 1) * 64 + l) * NCHUNK + (c + 1)];
            }
            const int k = s_k;
            if (col > c && k > 0) {              // cols <= c never re-read (and < c unwritten)
                uint64_t v = 0;
                for (int idx = g; idx < k; idx += 8) {
                    int l = s_keptlist[idx];
                    v |= mask[(size_t)(c * 64 + l) * NCHUNK + col];
                }
                if (v) {
                    atomicOr(&removed32[2 * col],     (uint32_t)v);
                    atomicOr(&removed32[2 * col + 1], (uint32_t)(v >> 32));
                }
            }
        }
        __syncthreads();
    }

    // ---- parallel output pass ----
    const int nch = s_nchunks;
    for (int cp = t >> 6; cp < nch; cp += 16) {
        uint64_t km = s_kmask[cp];
        if ((km >> lane) & 1) {
            int pos = s_kbase[cp] + __popcll(km & ((1ull << lane) - 1ull));
            if (pos < MAX_OUT) out[pos] = sidx[cp * 64 + lane];
        }
    }
    const int start = s_kept < MAX_OUT ? s_kept : MAX_OUT;
    for (int p = start + t; p < MAX_OUT; p += 1024) out[p] = -1;
}

// ---------------------------------------------------------------------------
extern "C" void kernel_launch(void* const* d_in, const int* in_sizes, int n_in,
                              void* d_out, int out_size, void* d_ws, size_t ws_size,
                              hipStream_t stream) {
    const float4* rois   = (const float4*)d_in[0];   // [8192,4] fp32
    const float*  scores = (const float*)d_in[1];    // [8192]   fp32
    int* out = (int*)d_out;                          // [300] int32

    // workspace layout (~8.6 MB)
    float4*   sboxes = (float4*)d_ws;                                   // 128 KiB
    int*      sidx   = (int*)((char*)d_ws + 128 * 1024);                //  32 KiB
    uint64_t* mask   = (uint64_t*)((char*)d_ws + 160 * 1024);           //   8 MiB
    int*      rank   = (int*)((char*)d_ws + 160 * 1024 + 8 * 1024 * 1024); // 32 KiB

    hipMemsetAsync(rank, 0, N * sizeof(int), stream);
    nms_rank_partial<<<dim3(32, 32), dim3(256), 0, stream>>>(scores, rank);
    nms_scatter<<<dim3(32), dim3(256), 0, stream>>>(rois, rank, sboxes, sidx);
    nms_mask<<<dim3(NCHUNK, NCHUNK), dim3(64), 0, stream>>>(sboxes, mask);
    nms_scan<<<dim3(1), dim3(1024), 0, stream>>>(mask, sidx, out);
}

// Round 5
// 126.146 us; speedup vs baseline: 3.7013x; 1.0774x over previous
//
#include <hip/hip_runtime.h>
#include <stdint.h>
#include <math.h>

// Must match numpy's unfused fp32 ops exactly: no FMA contraction in this TU.
#pragma clang fp contract(off)

#define N        8192
#define NCHUNK   128      // N / 64
#define MAX_OUT  300

// ---------------------------------------------------------------------------
// Phase 1a: partial rank counts, atomic-free. Block (bi,bj) writes its own
// slice rank32[bj][i]; scatter sums the 32 partials. Comparator: score desc,
// idx asc (unique keys -> ranks form a permutation).
// ---------------------------------------------------------------------------
__global__ void nms_rank_partial(const float* __restrict__ scores,
                                 int* __restrict__ rank32) {
    __shared__ uint32_t sk[256];
    const int tid = threadIdx.x;
    const int bi  = blockIdx.y, bj = blockIdx.x;
    const int jbase = bj * 256;

    sk[tid] = __float_as_uint(scores[jbase + tid]);  // scores >= 0 -> uint-monotonic
    __syncthreads();

    const int i = bi * 256 + tid;
    const uint32_t my = __float_as_uint(scores[i]);

    int cnt = 0;
    const uint4* sk4 = (const uint4*)sk;
    for (int jj = 0; jj < 64; ++jj) {          // 64 x b128 LDS broadcast reads
        uint4 v = sk4[jj];
        int j0 = jbase + jj * 4;
        cnt += (v.x > my) || (v.x == my && (j0 + 0) < i);
        cnt += (v.y > my) || (v.y == my && (j0 + 1) < i);
        cnt += (v.z > my) || (v.z == my && (j0 + 2) < i);
        cnt += (v.w > my) || (v.w == my && (j0 + 3) < i);
    }
    rank32[bj * N + i] = cnt;
}

// ---------------------------------------------------------------------------
// Phase 1b: sum partials, scatter boxes/indices into score-sorted order.
// ---------------------------------------------------------------------------
__global__ void nms_scatter(const float4* __restrict__ rois,
                            const int*    __restrict__ rank32,
                            float4* __restrict__ sboxes,
                            int*    __restrict__ sidx) {
    const int i = blockIdx.x * blockDim.x + threadIdx.x;
    int r = 0;
#pragma unroll
    for (int k = 0; k < 32; ++k) r += rank32[k * N + i];
    sboxes[r] = rois[i];
    sidx[r]   = i;
}

// ---------------------------------------------------------------------------
// Phase 2: suppression bitmask, TRANSPOSED layout maskT[colchunk][row].
// Lane c owns column bj*64+c (registers); loop rows from LDS broadcast.
// Suppress predicate via exact f64 compare (== fp32 IEEE div vs 0.5):
//   fl32(inter/denom) > 0.5  <=>  2*inter > denom*(1+2^-24)   (denom > 0)
// ballot(pred) IS the row's 64-bit word; lane r keeps row r's word ->
// one fully-coalesced 512B store per block.
// ---------------------------------------------------------------------------
__global__ void __launch_bounds__(64)
nms_mask(const float4* __restrict__ sboxes,
         uint64_t* __restrict__ maskT) {
    // decode linear block -> (bi,bj), bj >= bi  (8256 = 128*129/2 blocks)
    const int L = blockIdx.x;
    int bi = (int)(128.5 - sqrt(16512.25 - 2.0 * (double)L));
    if (bi < 0) bi = 0;
    if (bi > 127) bi = 127;
    while (bi < 127 && (bi + 1) * 128 - ((bi + 1) * bi) / 2 <= L) ++bi;
    while (bi > 0 && bi * 128 - (bi * (bi - 1)) / 2 > L) --bi;
    const int bj = bi + (L - (bi * 128 - (bi * (bi - 1)) / 2));

    const int lane = threadIdx.x;          // 0..63 = column within chunk bj
    const float4 cb = sboxes[bj * 64 + lane];
    const float  ac = (cb.z - cb.x) * (cb.w - cb.y);

    __shared__ float4 rb[64];
    __shared__ float  ra[64];
    {
        float4 t = sboxes[bi * 64 + lane];
        rb[lane] = t;
        ra[lane] = (t.z - t.x) * (t.w - t.y);
    }
    __syncthreads();

    const bool diag = (bi == bj);
    uint64_t myword = 0;
    for (int r = 0; r < 64; ++r) {
        const float4 b  = rb[r];           // LDS broadcast
        const float  ar = ra[r];
        float lx    = fmaxf(b.x, cb.x);
        float ly    = fmaxf(b.y, cb.y);
        float hx    = fminf(b.z, cb.z);
        float hy    = fminf(b.w, cb.w);
        float w     = fmaxf(hx - lx, 0.0f);
        float h     = fmaxf(hy - ly, 0.0f);
        float inter = w * h;
        float denom = (ar + ac) - inter;   // left-to-right like numpy
        double di = (double)inter, dd = (double)denom;
        bool sup = (2.0 * di) > (dd + dd * 0x1p-24);  // exact, == fl32(di/dd) > 0.5
        uint64_t word = __ballot(sup);
        if (diag)                          // keep only cols > r (wave-uniform)
            word &= (r == 63) ? 0ull : (~0ull << (r + 1));
        myword = (lane == r) ? word : myword;
    }
    // lane r stores row bi*64+r of column-chunk bj: 512B contiguous
    maskT[(size_t)bj * N + bi * 64 + lane] = myword;
}

// ---------------------------------------------------------------------------
// Phase 3: pipelined greedy scan, 1024 threads (indexing = transposed mask).
// ---------------------------------------------------------------------------
__global__ void __launch_bounds__(1024)
nms_scan(const uint64_t* __restrict__ maskT,
         const int*      __restrict__ sidx,
         int*            __restrict__ out) {
    __shared__ uint32_t removed32[2 * NCHUNK];   // removed bitmap, lo/hi pairs
    __shared__ uint64_t diag_lds[2][64];         // double-buffered diagonal words
    __shared__ uint64_t s_kmask[NCHUNK];         // per-chunk kept masks
    __shared__ int      s_kbase[NCHUNK];         // kept count before chunk
    __shared__ int      s_keptlist[64];          // kept lanes of current chunk
    __shared__ int      s_kept, s_done, s_nchunks, s_k;

    const int t    = threadIdx.x;
    const int lane = t & 63;

    if (t < 2 * NCHUNK) removed32[t] = 0;
    if (t < 64) diag_lds[0][t] = maskT[t];       // chunk 0 diag: maskT[0][0*64+t]
    __syncthreads();

    int kept = 0;                                // wave0-uniform mirror of s_kept
    for (int c = 0; c < NCHUNK; ++c) {
        // ---- Phase A: wave 0 resolves the in-chunk greedy chain ----
        if (t < 64) {
            uint64_t remw = (uint64_t)removed32[2 * c] |
                            ((uint64_t)removed32[2 * c + 1] << 32);
            uint64_t dg = diag_lds[c & 1][lane];
            uint64_t keptmask = 0;
            if (remw != ~0ull) {
#pragma unroll
                for (int l = 0; l < 64; ++l) {
                    uint64_t dl = __shfl((unsigned long long)dg, l, 64);
                    if (!((remw >> l) & 1)) remw |= dl;  // box l kept -> suppress in-chunk
                }
                keptmask = ~remw;
            }
            const int nk = __popcll(keptmask);
            if ((keptmask >> lane) & 1) {
                int lpos = __popcll(keptmask & ((1ull << lane) - 1ull));
                s_keptlist[lpos] = lane;
            }
            if (lane == 0) {
                s_kmask[c]  = keptmask;
                s_kbase[c]  = kept;
                s_k         = nk;
                int nkept   = kept + nk;
                s_kept      = nkept;
                s_done      = (nkept >= MAX_OUT) || (c == NCHUNK - 1);
                s_nchunks   = c + 1;
            }
            kept += nk;
        }
        __syncthreads();
        if (s_done) break;

        // ---- Phase B: parallel OR of kept rows into future columns ----
        {
            const int col = t & 127;
            const int g   = t >> 7;              // 0..7: 8 threads per column word
            if (t >= 64 && t < 128) {            // wave 1: prefetch next diag
                int l = t - 64;
                diag_lds[(c + 1) & 1][l] =
                    maskT[(size_t)(c + 1) * N + (c + 1) * 64 + l];
            }
            const int k = s_k;
            if (col > c && k > 0) {              // cols <= c never re-read
                uint64_t v = 0;
                for (int idx = g; idx < k; idx += 8) {
                    int l = s_keptlist[idx];
                    v |= maskT[(size_t)col * N + c * 64 + l];
                }
                if (v) {
                    atomicOr(&removed32[2 * col],     (uint32_t)v);
                    atomicOr(&removed32[2 * col + 1], (uint32_t)(v >> 32));
                }
            }
        }
        __syncthreads();
    }

    // ---- parallel output pass ----
    const int nch = s_nchunks;
    for (int cp = t >> 6; cp < nch; cp += 16) {
        uint64_t km = s_kmask[cp];
        if ((km >> lane) & 1) {
            int pos = s_kbase[cp] + __popcll(km & ((1ull << lane) - 1ull));
            if (pos < MAX_OUT) out[pos] = sidx[cp * 64 + lane];
        }
    }
    const int start = s_kept < MAX_OUT ? s_kept : MAX_OUT;
    for (int p = start + t; p < MAX_OUT; p += 1024) out[p] = -1;
}

// ---------------------------------------------------------------------------
extern "C" void kernel_launch(void* const* d_in, const int* in_sizes, int n_in,
                              void* d_out, int out_size, void* d_ws, size_t ws_size,
                              hipStream_t stream) {
    const float4* rois   = (const float4*)d_in[0];   // [8192,4] fp32
    const float*  scores = (const float*)d_in[1];    // [8192]   fp32
    int* out = (int*)d_out;                          // [300] int32

    // workspace layout (~9.3 MB)
    float4*   sboxes = (float4*)d_ws;                                      // 128 KiB
    int*      sidx   = (int*)((char*)d_ws + 128 * 1024);                   //  32 KiB
    uint64_t* maskT  = (uint64_t*)((char*)d_ws + 160 * 1024);              //   8 MiB
    int*      rank32 = (int*)((char*)d_ws + 160 * 1024 + 8 * 1024 * 1024); //   1 MiB

    nms_rank_partial<<<dim3(32, 32), dim3(256), 0, stream>>>(scores, rank32);
    nms_scatter<<<dim3(32), dim3(256), 0, stream>>>(rois, rank32, sboxes, sidx);
    nms_mask<<<dim3(8256), dim3(64), 0, stream>>>(sboxes, maskT);
    nms_scan<<<dim3(1), dim3(1024), 0, stream>>>(maskT, sidx, out);
}

// Round 6
// 116.401 us; speedup vs baseline: 4.0112x; 1.0837x over previous
//
#include <hip/hip_runtime.h>
#include <stdint.h>
#include <math.h>

// Must match numpy's unfused fp32 ops exactly: no FMA contraction in this TU.
#pragma clang fp contract(off)

#define N        8192
#define NCHUNK   128      // N / 64
#define NTILE    64       // 128-box tiles
#define MAX_OUT  300

// ---------------------------------------------------------------------------
// Phase 1a: partial rank counts, atomic-free. Block (bi,bj) writes its own
// slice rank32[bj][i]; scatter sums the 32 partials. Comparator: score desc,
// idx asc (unique keys -> ranks form a permutation).
// ---------------------------------------------------------------------------
__global__ void nms_rank_partial(const float* __restrict__ scores,
                                 int* __restrict__ rank32) {
    __shared__ uint32_t sk[256];
    const int tid = threadIdx.x;
    const int bi  = blockIdx.y, bj = blockIdx.x;
    const int jbase = bj * 256;

    sk[tid] = __float_as_uint(scores[jbase + tid]);  // scores >= 0 -> uint-monotonic
    __syncthreads();

    const int i = bi * 256 + tid;
    const uint32_t my = __float_as_uint(scores[i]);

    int cnt = 0;
    const uint4* sk4 = (const uint4*)sk;
    for (int jj = 0; jj < 64; ++jj) {          // 64 x b128 LDS broadcast reads
        uint4 v = sk4[jj];
        int j0 = jbase + jj * 4;
        cnt += (v.x > my) || (v.x == my && (j0 + 0) < i);
        cnt += (v.y > my) || (v.y == my && (j0 + 1) < i);
        cnt += (v.z > my) || (v.z == my && (j0 + 2) < i);
        cnt += (v.w > my) || (v.w == my && (j0 + 3) < i);
    }
    rank32[bj * N + i] = cnt;
}

// ---------------------------------------------------------------------------
// Phase 1b: sum partials, scatter boxes/indices into score-sorted order.
// ---------------------------------------------------------------------------
__global__ void nms_scatter(const float4* __restrict__ rois,
                            const int*    __restrict__ rank32,
                            float4* __restrict__ sboxes,
                            int*    __restrict__ sidx) {
    const int i = blockIdx.x * blockDim.x + threadIdx.x;
    int r = 0;
#pragma unroll
    for (int k = 0; k < 32; ++k) r += rank32[k * N + i];
    sboxes[r] = rois[i];
    sidx[r]   = i;
}

// ---------------------------------------------------------------------------
// Phase 2: suppression bitmask, transposed layout maskT[colchunk][row].
// Exact f64 compare == fp32 IEEE div vs 0.5 (verified bit-exact R4/R5).
// ---------------------------------------------------------------------------
__global__ void __launch_bounds__(64)
nms_mask(const float4* __restrict__ sboxes,
         uint64_t* __restrict__ maskT) {
    // decode linear block -> (bi,bj), bj >= bi  (8256 = 128*129/2 blocks)
    const int L = blockIdx.x;
    int bi = (int)(128.5 - sqrt(16512.25 - 2.0 * (double)L));
    if (bi < 0) bi = 0;
    if (bi > 127) bi = 127;
    while (bi < 127 && (bi + 1) * 128 - ((bi + 1) * bi) / 2 <= L) ++bi;
    while (bi > 0 && bi * 128 - (bi * (bi - 1)) / 2 > L) --bi;
    const int bj = bi + (L - (bi * 128 - (bi * (bi - 1)) / 2));

    const int lane = threadIdx.x;          // 0..63 = column within chunk bj
    const float4 cb = sboxes[bj * 64 + lane];
    const float  ac = (cb.z - cb.x) * (cb.w - cb.y);

    __shared__ float4 rb[64];
    __shared__ float  ra[64];
    {
        float4 t = sboxes[bi * 64 + lane];
        rb[lane] = t;
        ra[lane] = (t.z - t.x) * (t.w - t.y);
    }
    __syncthreads();

    const bool diag = (bi == bj);
    uint64_t myword = 0;
    for (int r = 0; r < 64; ++r) {
        const float4 b  = rb[r];           // LDS broadcast
        const float  ar = ra[r];
        float lx    = fmaxf(b.x, cb.x);
        float ly    = fmaxf(b.y, cb.y);
        float hx    = fminf(b.z, cb.z);
        float hy    = fminf(b.w, cb.w);
        float w     = fmaxf(hx - lx, 0.0f);
        float h     = fmaxf(hy - ly, 0.0f);
        float inter = w * h;
        float denom = (ar + ac) - inter;   // left-to-right like numpy
        double di = (double)inter, dd = (double)denom;
        bool sup = (di + di) > (dd + dd * 0x1p-24);  // exact: fl32(di/dd) > 0.5
        uint64_t word = __ballot(sup);
        if (diag)                          // keep only cols > r (wave-uniform)
            word &= (r == 63) ? 0ull : (~0ull << (r + 1));
        myword = (lane == r) ? word : myword;
    }
    maskT[(size_t)bj * N + bi * 64 + lane] = myword;   // 512B coalesced store
}

// ---------------------------------------------------------------------------
// Phase 3: pipelined greedy scan. 64 tiles x 128 boxes, ONE barrier/iter.
//  wave 0 : resolve tile it (scalar ff1 chain, dynamic readlane) + fold the
//           *next* tile's removed words directly (Y readlanes) -> next A does
//           not depend on this iter's B.
//  wave 1 : prefetch tile it+1 words (D0,D1,X,Y0a,Y0b,Y1a,Y1b) into LDS dbuf.
//  waves 2-15 : apply tile it-1's kept rows to cols >= 2it+4 (parallel RT).
// ---------------------------------------------------------------------------
__device__ __forceinline__ uint64_t rl64(uint64_t v, int l) {
    uint32_t lo = (uint32_t)__builtin_amdgcn_readlane((int)(uint32_t)v, l);
    uint32_t hi = (uint32_t)__builtin_amdgcn_readlane((int)(uint32_t)(v >> 32), l);
    return ((uint64_t)hi << 32) | lo;
}

__global__ void __launch_bounds__(1024)
nms_scan(const uint64_t* __restrict__ maskT,
         const int*      __restrict__ sidx,
         int*            __restrict__ out) {
    __shared__ uint32_t removed32[2 * NCHUNK];   // per-chunk removed, lo/hi pairs
    __shared__ uint64_t pf[2][7][64];            // dbuf: D0,D1,X,Y0a,Y0b,Y1a,Y1b
    __shared__ uint64_t s_kmask[NCHUNK];
    __shared__ int      s_kbase[NCHUNK];
    __shared__ int      s_keptlist[2][128];      // absolute sorted-rows, dbuf
    __shared__ int      s_k[2];
    __shared__ int      s_kept, s_done, s_nch;

    const int t    = threadIdx.x;
    const int lane = t & 63;
    const int wave = t >> 6;

    if (t < 2 * NCHUNK) removed32[t] = 0;
    if (t == 0) { s_kept = 0; s_done = 0; s_nch = 0; s_k[0] = 0; s_k[1] = 0; }
    if (wave == 1) {                             // prefetch tile 0 into pf[0]
        pf[0][0][lane] = maskT[(size_t)0 * N + 0 * 64 + lane];   // D0 (diag c0)
        pf[0][1][lane] = maskT[(size_t)1 * N + 1 * 64 + lane];   // D1 (diag c1)
        pf[0][2][lane] = maskT[(size_t)1 * N + 0 * 64 + lane];   // X  (c0 rows @ c1)
        pf[0][3][lane] = maskT[(size_t)2 * N + 0 * 64 + lane];   // Y0a (c0 rows @ col2)
        pf[0][4][lane] = maskT[(size_t)2 * N + 1 * 64 + lane];   // Y0b (c1 rows @ col2)
        pf[0][5][lane] = maskT[(size_t)3 * N + 0 * 64 + lane];   // Y1a (c0 rows @ col3)
        pf[0][6][lane] = maskT[(size_t)3 * N + 1 * 64 + lane];   // Y1b (c1 rows @ col3)
    }
    __syncthreads();

    for (int it = 0; it < NTILE; ++it) {
        const int c0 = 2 * it, c1 = 2 * it + 1;
        const int buf = it & 1;

        if (wave == 0) {
            // ---- A: resolve tile it ----
            uint64_t D0  = pf[buf][0][lane], D1  = pf[buf][1][lane];
            uint64_t X   = pf[buf][2][lane];
            uint64_t Y0a = pf[buf][3][lane], Y0b = pf[buf][4][lane];
            uint64_t Y1a = pf[buf][5][lane], Y1b = pf[buf][6][lane];
            uint64_t rem0 = (uint64_t)removed32[2 * c0] | ((uint64_t)removed32[2 * c0 + 1] << 32);
            uint64_t rem1 = (uint64_t)removed32[2 * c1] | ((uint64_t)removed32[2 * c1 + 1] << 32);
            uint64_t keep0 = 0, keep1 = 0, xw = 0, y0 = 0, y1 = 0;

            uint64_t cand = ~rem0;                 // chunk c0 greedy chain
            while (cand) {
                int l = __builtin_ctzll(cand);
                keep0 |= (1ull << l);
                uint64_t d = rl64(D0, l);
                xw |= rl64(X, l);
                y0 |= rl64(Y0a, l);
                y1 |= rl64(Y1a, l);
                cand &= ~d;
                cand &= ~(1ull << l);
            }
            rem1 |= xw;
            cand = ~rem1;                          // chunk c1 greedy chain
            while (cand) {
                int l = __builtin_ctzll(cand);
                keep1 |= (1ull << l);
                uint64_t d = rl64(D1, l);
                y0 |= rl64(Y0b, l);
                y1 |= rl64(Y1b, l);
                cand &= ~d;
                cand &= ~(1ull << l);
            }
            // fold urgent removed-updates for next tile (atomic: B also writes)
            if (c0 + 2 < NCHUNK && y0) {
                atomicOr(&removed32[2 * (c0 + 2)],     (uint32_t)y0);
                atomicOr(&removed32[2 * (c0 + 2) + 1], (uint32_t)(y0 >> 32));
            }
            if (c0 + 3 < NCHUNK && y1) {
                atomicOr(&removed32[2 * (c0 + 3)],     (uint32_t)y1);
                atomicOr(&removed32[2 * (c0 + 3) + 1], (uint32_t)(y1 >> 32));
            }
            const int n0 = __popcll(keep0), n1 = __popcll(keep1);
            const int base = s_kept;               // uniform read (write below is later)
            if ((keep0 >> lane) & 1) {
                int p = __popcll(keep0 & ((1ull << lane) - 1ull));
                s_keptlist[buf][p] = c0 * 64 + lane;
            }
            if ((keep1 >> lane) & 1) {
                int p = n0 + __popcll(keep1 & ((1ull << lane) - 1ull));
                s_keptlist[buf][p] = c1 * 64 + lane;
            }
            if (lane == 0) {
                s_kmask[c0] = keep0;  s_kmask[c1] = keep1;
                s_kbase[c0] = base;   s_kbase[c1] = base + n0;
                s_k[buf]    = n0 + n1;
                int nk      = base + n0 + n1;
                s_kept      = nk;
                s_nch       = c1 + 1;
                if (nk >= MAX_OUT || it == NTILE - 1) s_done = 1;
            }
        } else if (wave == 1) {
            // ---- prefetch tile it+1 into pf[buf^1] ----
            const int p0 = 2 * it + 2, p1 = 2 * it + 3;
            const int m0 = 2 * it + 4, m1 = 2 * it + 5;
            if (p0 < NCHUNK) {
                pf[buf ^ 1][0][lane] = maskT[(size_t)p0 * N + p0 * 64 + lane];
                pf[buf ^ 1][1][lane] = maskT[(size_t)p1 * N + p1 * 64 + lane];
                pf[buf ^ 1][2][lane] = maskT[(size_t)p1 * N + p0 * 64 + lane];
                if (m0 < NCHUNK) {
                    pf[buf ^ 1][3][lane] = maskT[(size_t)m0 * N + p0 * 64 + lane];
                    pf[buf ^ 1][4][lane] = maskT[(size_t)m0 * N + p1 * 64 + lane];
                    pf[buf ^ 1][5][lane] = maskT[(size_t)m1 * N + p0 * 64 + lane];
                    pf[buf ^ 1][6][lane] = maskT[(size_t)m1 * N + p1 * 64 + lane];
                }
            }
        } else {
            // ---- B: apply tile it-1's kept rows to cols >= 2it+2 ----
            if (it >= 1) {
                const int k = s_k[buf ^ 1];
                const int col = t & 127;           // waves 2..15: 7 groups x 128 cols
                const int g   = (t >> 7) - 1;      // 0..6
                const int colmin = 2 * it + 2;     // cols 2it,2it+1 read-only now;
                                                   // 2it+2,2it+3 handled by A folds
                if (k > 0 && col >= colmin && col < NCHUNK) {
                    uint64_t v = 0;
                    for (int idx = g; idx < k; idx += 7) {
                        int row = s_keptlist[buf ^ 1][idx];
                        v |= maskT[(size_t)col * N + row];
                    }
                    if (v) {
                        atomicOr(&removed32[2 * col],     (uint32_t)v);
                        atomicOr(&removed32[2 * col + 1], (uint32_t)(v >> 32));
                    }
                }
            }
        }
        __syncthreads();
        if (s_done) break;
    }

    // ---- parallel output pass ----
    const int nch = s_nch;
    for (int cp = t >> 6; cp < nch; cp += 16) {
        uint64_t km = s_kmask[cp];
        if ((km >> lane) & 1) {
            int pos = s_kbase[cp] + __popcll(km & ((1ull << lane) - 1ull));
            if (pos < MAX_OUT) out[pos] = sidx[cp * 64 + lane];
        }
    }
    const int start = s_kept < MAX_OUT ? s_kept : MAX_OUT;
    for (int p = start + t; p < MAX_OUT; p += 1024) out[p] = -1;
}

// ---------------------------------------------------------------------------
extern "C" void kernel_launch(void* const* d_in, const int* in_sizes, int n_in,
                              void* d_out, int out_size, void* d_ws, size_t ws_size,
                              hipStream_t stream) {
    const float4* rois   = (const float4*)d_in[0];   // [8192,4] fp32
    const float*  scores = (const float*)d_in[1];    // [8192]   fp32
    int* out = (int*)d_out;                          // [300] int32

    // workspace layout (~9.3 MB)
    float4*   sboxes = (float4*)d_ws;                                      // 128 KiB
    int*      sidx   = (int*)((char*)d_ws + 128 * 1024);                   //  32 KiB
    uint64_t* maskT  = (uint64_t*)((char*)d_ws + 160 * 1024);              //   8 MiB
    int*      rank32 = (int*)((char*)d_ws + 160 * 1024 + 8 * 1024 * 1024); //   1 MiB

    nms_rank_partial<<<dim3(32, 32), dim3(256), 0, stream>>>(scores, rank32);
    nms_scatter<<<dim3(32), dim3(256), 0, stream>>>(rois, rank32, sboxes, sidx);
    nms_mask<<<dim3(8256), dim3(64), 0, stream>>>(sboxes, maskT);
    nms_scan<<<dim3(1), dim3(1024), 0, stream>>>(maskT, sidx, out);
}